// Round 2
// baseline (233.083 us; speedup 1.0000x reference)
//
#include <hip/hip_runtime.h>
#include <stdint.h>

// Binary conv via bit-pack + XNOR popcount, interior/border specialized.
// A: [32,64,112,112] f32, W: [64,64,3,3] f32 (flat), out: [32,64,112,112] f32.
// sign bit = signbit(x); dot over 64 ch = 64 - 2*popc(a ^ w).
// Interior (h in [1,110], w in [2,109]): no padding masks, 2 pixels/thread.
// Border: masked 1-pixel path, tiny volume.

#define NN 32
#define CC 64
#define HH 112
#define WW 112
#define OO 64
#define HW (HH*WW)       // 12544
#define NHW (NN*HW)      // 401408

#define PACK_BLOCK 256
#define PACK_A_BLOCKS (NHW/4/PACK_BLOCK)   // 392

// interior: rows h=1..110, pixel pairs w0=2,4,...,108 (covers w=2..109)
#define INT_GPR 54                  // pairs per row
#define INT_ROWS 110
#define INT_GPI (INT_GPR*INT_ROWS)  // 5940 per image
#define INT_THREADS (NN*INT_GPI)    // 190080
#define INT_BLOCKS ((INT_THREADS+255)/256) // 743

#define BOR_PPI 664                 // border pixels per image (2*112 + 110*4)
#define BOR_THREADS (NN*BOR_PPI)    // 21248
#define BOR_BLOCKS (BOR_THREADS/256) // 83

#define CONV_BLOCKS (BOR_BLOCKS + INT_BLOCKS) // 826

__global__ __launch_bounds__(PACK_BLOCK)
void pack_kernel(const float* __restrict__ act, const float* __restrict__ wgt,
                 uint64_t* __restrict__ ap, uint64_t* __restrict__ wp) {
    int b = blockIdx.x;
    if (b == PACK_A_BLOCKS) {
        // ---- pack weights: wp[o*9+k] bit i = signbit(W[o][i][kh][kw]) ----
        for (int t = threadIdx.x; t < OO * 9; t += PACK_BLOCK) {
            int o = t / 9, k = t - o * 9;
            uint32_t lo = 0, hi = 0;
            #pragma unroll
            for (int i = 0; i < 64; ++i) {
                uint32_t s = __float_as_uint(wgt[(o * 64 + i) * 9 + k]) >> 31;
                if (i < 32) lo |= s << i;
                else        hi |= s << (i - 32);
            }
            wp[t] = ((uint64_t)hi << 32) | lo;
        }
        return;
    }
    // ---- pack activations: 4 pixels (float4 across w) per thread ----
    int t = b * PACK_BLOCK + threadIdx.x;        // float4-group id over N*HW/4
    int n = t / (HW / 4);
    int rem4 = t - n * (HW / 4);
    const float4* base = (const float4*)act + (size_t)n * CC * (HW / 4) + rem4;
    uint32_t lo[4] = {0, 0, 0, 0}, hi[4] = {0, 0, 0, 0};
    #pragma unroll
    for (int c = 0; c < 64; ++c) {
        float4 v = base[(size_t)c * (HW / 4)];   // coalesced: 64 lanes x 16B
        uint32_t s0 = __float_as_uint(v.x) >> 31;
        uint32_t s1 = __float_as_uint(v.y) >> 31;
        uint32_t s2 = __float_as_uint(v.z) >> 31;
        uint32_t s3 = __float_as_uint(v.w) >> 31;
        if (c < 32) {
            lo[0] |= s0 << c; lo[1] |= s1 << c; lo[2] |= s2 << c; lo[3] |= s3 << c;
        } else {
            int cc = c - 32;
            hi[0] |= s0 << cc; hi[1] |= s1 << cc; hi[2] |= s2 << cc; hi[3] |= s3 << cc;
        }
    }
    ulonglong2 w01, w23;
    w01.x = ((uint64_t)hi[0] << 32) | lo[0];
    w01.y = ((uint64_t)hi[1] << 32) | lo[1];
    w23.x = ((uint64_t)hi[2] << 32) | lo[2];
    w23.y = ((uint64_t)hi[3] << 32) | lo[3];
    ulonglong2* dst = (ulonglong2*)(ap + (size_t)t * 4);
    dst[0] = w01;
    dst[1] = w23;
}

__global__ __launch_bounds__(256)
void conv_kernel(const uint64_t* __restrict__ ap, const uint64_t* __restrict__ wp,
                 float* __restrict__ out) {
    if (blockIdx.x >= BOR_BLOCKS) {
        // ================= interior: 2 pixels/thread, no masks =================
        int t = (blockIdx.x - BOR_BLOCKS) * 256 + threadIdx.x;
        if (t >= INT_THREADS) return;
        int n = t / INT_GPI;
        int rem = t - n * INT_GPI;
        int hr = rem / INT_GPR;
        int gw = rem - hr * INT_GPR;
        int h = hr + 1;
        int w0 = 2 + 2 * gw;                     // covers pixels w0, w0+1
        const uint64_t* apn = ap + (size_t)n * HW + (h - 1) * WW + (w0 - 1);
        uint64_t a[3][4];
        #pragma unroll
        for (int r = 0; r < 3; ++r)
            #pragma unroll
            for (int c = 0; c < 4; ++c)
                a[r][c] = apn[r * WW + c];
        float* op = out + (size_t)n * (OO * HW) + h * WW + w0;
        for (int o = 0; o < OO; ++o) {
            const uint64_t* wk = wp + o * 9;     // uniform -> scalar loads
            int s0 = 0, s1 = 0;
            #pragma unroll
            for (int r = 0; r < 3; ++r)
                #pragma unroll
                for (int c = 0; c < 3; ++c) {
                    uint64_t w = wk[r * 3 + c];
                    s0 += __popcll(a[r][c]     ^ w);
                    s1 += __popcll(a[r][c + 1] ^ w);
                }
            float2 v = make_float2((float)(576 - 2 * s0), (float)(576 - 2 * s1));
            *(float2*)(op + (size_t)o * HW) = v;
        }
        return;
    }
    // ================= border: 1 pixel/thread, masked =================
    int t = blockIdx.x * 256 + threadIdx.x;      // [0, BOR_THREADS)
    int n = t / BOR_PPI;
    int b = t - n * BOR_PPI;
    int h, w;
    if (b < 112)      { h = 0;   w = b; }
    else if (b < 224) { h = 111; w = b - 112; }
    else {
        int c = b - 224;
        h = 1 + (c >> 2);
        int q = c & 3;
        w = q + ((q >= 2) ? 108 : 0);            // q:0->0, 1->1, 2->110, 3->111
    }
    const uint64_t* apn = ap + (size_t)n * HW;
    uint64_t a[9], m[9];
    int nvalid = 0;
    #pragma unroll
    for (int kh = 0; kh < 3; ++kh) {
        int hh = h + kh - 1;
        bool hv = (unsigned)hh < (unsigned)HH;
        #pragma unroll
        for (int kw = 0; kw < 3; ++kw) {
            int ww2 = w + kw - 1;
            bool wv = (unsigned)ww2 < (unsigned)WW;
            bool v = hv && wv;
            int k = kh * 3 + kw;
            int ch = hv ? hh : h;                // clamped (safe) address
            int cw = wv ? ww2 : w;
            a[k] = apn[ch * WW + cw];
            m[k] = v ? ~0ull : 0ull;
            nvalid += v ? 1 : 0;
        }
    }
    int base = 64 * nvalid;
    float* op = out + (size_t)n * (OO * HW) + h * WW + w;
    for (int o = 0; o < OO; ++o) {
        const uint64_t* wk = wp + o * 9;
        int s = 0;
        #pragma unroll
        for (int k = 0; k < 9; ++k)
            s += __popcll((a[k] ^ wk[k]) & m[k]);
        op[(size_t)o * HW] = (float)(base - 2 * s);
    }
}

extern "C" void kernel_launch(void* const* d_in, const int* in_sizes, int n_in,
                              void* d_out, int out_size, void* d_ws, size_t ws_size,
                              hipStream_t stream) {
    const float* act = (const float*)d_in[0];
    const float* wgt = (const float*)d_in[1];
    float* out = (float*)d_out;

    uint64_t* wp = (uint64_t*)d_ws;          // 576 words (rounded to 1024)
    uint64_t* ap = wp + 1024;                // 401408 words (~3.2 MB)

    pack_kernel<<<PACK_A_BLOCKS + 1, PACK_BLOCK, 0, stream>>>(act, wgt, ap, wp);
    conv_kernel<<<CONV_BLOCKS, 256, 0, stream>>>(ap, wp, out);
}

// Round 4
// 230.654 us; speedup vs baseline: 1.0105x; 1.0105x over previous
//
#include <hip/hip_runtime.h>
#include <stdint.h>

// Binary conv via bit-pack + XNOR popcount, interior/border specialized.
// A: [32,64,112,112] f32, W: [64,64,3,3] f32 (flat), out: [32,64,112,112] f32.
// sign bit = signbit(x); dot over 64 ch = 64 - 2*popc(a ^ w).
// R4: nontemporal streaming via clang ext_vector types (HIP_vector_type is
// rejected by __builtin_nontemporal_*). Packed intermediate stays cacheable.

#define NN 32
#define CC 64
#define HH 112
#define WW 112
#define OO 64
#define HW (HH*WW)       // 12544
#define NHW (NN*HW)      // 401408

typedef float  vfloat4 __attribute__((ext_vector_type(4)));
typedef float  vfloat2 __attribute__((ext_vector_type(2)));

#define PACK_BLOCK 256
#define PACK_A_BLOCKS (NHW/4/PACK_BLOCK)   // 392

// interior: rows h=1..110, pixel pairs w0=2,4,...,108 (covers w=2..109)
#define INT_GPR 54                  // pairs per row
#define INT_ROWS 110
#define INT_GPI (INT_GPR*INT_ROWS)  // 5940 per image
#define INT_THREADS (NN*INT_GPI)    // 190080
#define INT_BLOCKS ((INT_THREADS+255)/256) // 743

#define BOR_PPI 664                 // border pixels per image (2*112 + 110*4)
#define BOR_THREADS (NN*BOR_PPI)    // 21248
#define BOR_BLOCKS (BOR_THREADS/256) // 83

#define CONV_BLOCKS (BOR_BLOCKS + INT_BLOCKS) // 826

__global__ __launch_bounds__(PACK_BLOCK)
void pack_kernel(const float* __restrict__ act, const float* __restrict__ wgt,
                 uint64_t* __restrict__ ap, uint64_t* __restrict__ wp) {
    int b = blockIdx.x;
    if (b == PACK_A_BLOCKS) {
        // ---- pack weights: wp[o*9+k] bit i = signbit(W[o][i][kh][kw]) ----
        for (int t = threadIdx.x; t < OO * 9; t += PACK_BLOCK) {
            int o = t / 9, k = t - o * 9;
            uint32_t lo = 0, hi = 0;
            #pragma unroll
            for (int i = 0; i < 64; ++i) {
                uint32_t s = __float_as_uint(wgt[(o * 64 + i) * 9 + k]) >> 31;
                if (i < 32) lo |= s << i;
                else        hi |= s << (i - 32);
            }
            wp[t] = ((uint64_t)hi << 32) | lo;
        }
        return;
    }
    // ---- pack activations: 4 pixels (float4 across w) per thread ----
    int t = b * PACK_BLOCK + threadIdx.x;        // float4-group id over N*HW/4
    int n = t / (HW / 4);
    int rem4 = t - n * (HW / 4);
    const vfloat4* base = (const vfloat4*)act + (size_t)n * CC * (HW / 4) + rem4;
    uint32_t lo[4] = {0, 0, 0, 0}, hi[4] = {0, 0, 0, 0};
    #pragma unroll
    for (int c = 0; c < 64; ++c) {
        vfloat4 v = __builtin_nontemporal_load(base + (size_t)c * (HW / 4));
        uint32_t s0 = __float_as_uint(v.x) >> 31;
        uint32_t s1 = __float_as_uint(v.y) >> 31;
        uint32_t s2 = __float_as_uint(v.z) >> 31;
        uint32_t s3 = __float_as_uint(v.w) >> 31;
        if (c < 32) {
            lo[0] |= s0 << c; lo[1] |= s1 << c; lo[2] |= s2 << c; lo[3] |= s3 << c;
        } else {
            int cc = c - 32;
            hi[0] |= s0 << cc; hi[1] |= s1 << cc; hi[2] |= s2 << cc; hi[3] |= s3 << cc;
        }
    }
    ulonglong2 w01, w23;
    w01.x = ((uint64_t)hi[0] << 32) | lo[0];
    w01.y = ((uint64_t)hi[1] << 32) | lo[1];
    w23.x = ((uint64_t)hi[2] << 32) | lo[2];
    w23.y = ((uint64_t)hi[3] << 32) | lo[3];
    ulonglong2* dst = (ulonglong2*)(ap + (size_t)t * 4);
    dst[0] = w01;                // cacheable: conv re-reads these from L2
    dst[1] = w23;
}

__global__ __launch_bounds__(256)
void conv_kernel(const uint64_t* __restrict__ ap, const uint64_t* __restrict__ wp,
                 float* __restrict__ out) {
    if (blockIdx.x >= BOR_BLOCKS) {
        // ================= interior: 2 pixels/thread, no masks =================
        int t = (blockIdx.x - BOR_BLOCKS) * 256 + threadIdx.x;
        if (t >= INT_THREADS) return;
        int n = t / INT_GPI;
        int rem = t - n * INT_GPI;
        int hr = rem / INT_GPR;
        int gw = rem - hr * INT_GPR;
        int h = hr + 1;
        int w0 = 2 + 2 * gw;                     // covers pixels w0, w0+1
        const uint64_t* apn = ap + (size_t)n * HW + (h - 1) * WW + (w0 - 1);
        uint64_t a[3][4];
        #pragma unroll
        for (int r = 0; r < 3; ++r)
            #pragma unroll
            for (int c = 0; c < 4; ++c)
                a[r][c] = apn[r * WW + c];
        float* op = out + (size_t)n * (OO * HW) + h * WW + w0;
        for (int o = 0; o < OO; ++o) {
            const uint64_t* wk = wp + o * 9;     // uniform -> scalar loads
            int s0 = 0, s1 = 0;
            #pragma unroll
            for (int r = 0; r < 3; ++r)
                #pragma unroll
                for (int c = 0; c < 3; ++c) {
                    uint64_t w = wk[r * 3 + c];
                    s0 += __popcll(a[r][c]     ^ w);
                    s1 += __popcll(a[r][c + 1] ^ w);
                }
            vfloat2 v = {(float)(576 - 2 * s0), (float)(576 - 2 * s1)};
            __builtin_nontemporal_store(v, (vfloat2*)(op + (size_t)o * HW));
        }
        return;
    }
    // ================= border: 1 pixel/thread, masked =================
    int t = blockIdx.x * 256 + threadIdx.x;      // [0, BOR_THREADS)
    int n = t / BOR_PPI;
    int b = t - n * BOR_PPI;
    int h, w;
    if (b < 112)      { h = 0;   w = b; }
    else if (b < 224) { h = 111; w = b - 112; }
    else {
        int c = b - 224;
        h = 1 + (c >> 2);
        int q = c & 3;
        w = q + ((q >= 2) ? 108 : 0);            // q:0->0, 1->1, 2->110, 3->111
    }
    const uint64_t* apn = ap + (size_t)n * HW;
    uint64_t a[9], m[9];
    int nvalid = 0;
    #pragma unroll
    for (int kh = 0; kh < 3; ++kh) {
        int hh = h + kh - 1;
        bool hv = (unsigned)hh < (unsigned)HH;
        #pragma unroll
        for (int kw = 0; kw < 3; ++kw) {
            int ww2 = w + kw - 1;
            bool wv = (unsigned)ww2 < (unsigned)WW;
            bool v = hv && wv;
            int k = kh * 3 + kw;
            int ch = hv ? hh : h;                // clamped (safe) address
            int cw = wv ? ww2 : w;
            a[k] = apn[ch * WW + cw];
            m[k] = v ? ~0ull : 0ull;
            nvalid += v ? 1 : 0;
        }
    }
    int base = 64 * nvalid;
    float* op = out + (size_t)n * (OO * HW) + h * WW + w;
    for (int o = 0; o < OO; ++o) {
        const uint64_t* wk = wp + o * 9;
        int s = 0;
        #pragma unroll
        for (int k = 0; k < 9; ++k)
            s += __popcll((a[k] ^ wk[k]) & m[k]);
        __builtin_nontemporal_store((float)(base - 2 * s), op + (size_t)o * HW);
    }
}

extern "C" void kernel_launch(void* const* d_in, const int* in_sizes, int n_in,
                              void* d_out, int out_size, void* d_ws, size_t ws_size,
                              hipStream_t stream) {
    const float* act = (const float*)d_in[0];
    const float* wgt = (const float*)d_in[1];
    float* out = (float*)d_out;

    uint64_t* wp = (uint64_t*)d_ws;          // 576 words (rounded to 1024)
    uint64_t* ap = wp + 1024;                // 401408 words (~3.2 MB)

    pack_kernel<<<PACK_A_BLOCKS + 1, PACK_BLOCK, 0, stream>>>(act, wgt, ap, wp);
    conv_kernel<<<CONV_BLOCKS, 256, 0, stream>>>(ap, wp, out);
}

// Round 5
// 221.109 us; speedup vs baseline: 1.0542x; 1.0432x over previous
//
#include <hip/hip_runtime.h>
#include <stdint.h>

// Binary conv via bit-pack + XNOR popcount, interior/border specialized.
// A: [32,64,112,112] f32, W: [64,64,3,3] f32 (flat), out: [32,64,112,112] f32.
// sign bit = signbit(x); dot over 64 ch = 64 - 2*popc(a ^ w).
// R5: conv parallelism 4x (2 pixels x 16 o-channels per thread, o-group
// wave-uniform via readfirstlane so weights stay scalar loads). Conv stores
// back to cacheable (nt caused +22% HBM write amplification on partial rows
// + defeated L2 merge). nt kept only on the read-once pack input.

#define NN 32
#define CC 64
#define HH 112
#define WW 112
#define OO 64
#define HW (HH*WW)       // 12544
#define NHW (NN*HW)      // 401408

typedef float  vfloat4 __attribute__((ext_vector_type(4)));

#define PACK_BLOCK 256
#define PACK_A_BLOCKS (NHW/4/PACK_BLOCK)   // 392

#define OG  4                // o-groups per pixel
#define OPG 16               // o-channels per group (OG*OPG == OO)

// interior: rows h=1..110, pixel pairs w0=2,4,...,108 (covers w=2..109)
#define INT_GPR 54                    // pairs per row
#define INT_ROWS 110
#define INT_GPI (INT_GPR*INT_ROWS)    // 5940 per image
#define INT_PAIRS (NN*INT_GPI)        // 190080  (multiple of 64: /64 = 2970)
#define INT_THREADS (INT_PAIRS*OG)    // 760320
#define INT_BLOCKS (INT_THREADS/256)  // 2970

#define BOR_PPI 664                   // border pixels per image
#define BOR_TOT (NN*BOR_PPI)          // 21248   (multiple of 64: /64 = 332)
#define BOR_THREADS (BOR_TOT*OG)      // 84992
#define BOR_BLOCKS (BOR_THREADS/256)  // 332

#define CONV_BLOCKS (BOR_BLOCKS + INT_BLOCKS) // 3302

__global__ __launch_bounds__(PACK_BLOCK)
void pack_kernel(const float* __restrict__ act, const float* __restrict__ wgt,
                 uint64_t* __restrict__ ap, uint64_t* __restrict__ wp) {
    int b = blockIdx.x;
    if (b == PACK_A_BLOCKS) {
        // ---- pack weights: wp[o*9+k] bit i = signbit(W[o][i][kh][kw]) ----
        for (int t = threadIdx.x; t < OO * 9; t += PACK_BLOCK) {
            int o = t / 9, k = t - o * 9;
            uint32_t lo = 0, hi = 0;
            #pragma unroll
            for (int i = 0; i < 64; ++i) {
                uint32_t s = __float_as_uint(wgt[(o * 64 + i) * 9 + k]) >> 31;
                if (i < 32) lo |= s << i;
                else        hi |= s << (i - 32);
            }
            wp[t] = ((uint64_t)hi << 32) | lo;
        }
        return;
    }
    // ---- pack activations: 4 pixels (float4 across w) per thread ----
    int t = b * PACK_BLOCK + threadIdx.x;        // float4-group id over N*HW/4
    int n = t / (HW / 4);
    int rem4 = t - n * (HW / 4);
    const vfloat4* base = (const vfloat4*)act + (size_t)n * CC * (HW / 4) + rem4;
    uint32_t lo[4] = {0, 0, 0, 0}, hi[4] = {0, 0, 0, 0};
    #pragma unroll
    for (int c = 0; c < 64; ++c) {
        vfloat4 v = __builtin_nontemporal_load(base + (size_t)c * (HW / 4));
        uint32_t s0 = __float_as_uint(v.x) >> 31;
        uint32_t s1 = __float_as_uint(v.y) >> 31;
        uint32_t s2 = __float_as_uint(v.z) >> 31;
        uint32_t s3 = __float_as_uint(v.w) >> 31;
        if (c < 32) {
            lo[0] |= s0 << c; lo[1] |= s1 << c; lo[2] |= s2 << c; lo[3] |= s3 << c;
        } else {
            int cc = c - 32;
            hi[0] |= s0 << cc; hi[1] |= s1 << cc; hi[2] |= s2 << cc; hi[3] |= s3 << cc;
        }
    }
    ulonglong2 w01, w23;
    w01.x = ((uint64_t)hi[0] << 32) | lo[0];
    w01.y = ((uint64_t)hi[1] << 32) | lo[1];
    w23.x = ((uint64_t)hi[2] << 32) | lo[2];
    w23.y = ((uint64_t)hi[3] << 32) | lo[3];
    ulonglong2* dst = (ulonglong2*)(ap + (size_t)t * 4);
    dst[0] = w01;                // cacheable: conv re-reads these from L2
    dst[1] = w23;
}

__global__ __launch_bounds__(256)
void conv_kernel(const uint64_t* __restrict__ ap, const uint64_t* __restrict__ wp,
                 float* __restrict__ out) {
    if (blockIdx.x >= BOR_BLOCKS) {
        // ========= interior: 2 pixels x 16 o-channels per thread, no masks =========
        int t = (blockIdx.x - BOR_BLOCKS) * 256 + threadIdx.x;
        // o-group: waves never straddle (INT_PAIRS % 64 == 0) -> wave-uniform
        int og = __builtin_amdgcn_readfirstlane(t / INT_PAIRS);
        int r = t - og * INT_PAIRS;
        int n = r / INT_GPI;
        int rem = r - n * INT_GPI;
        int hr = rem / INT_GPR;
        int gw = rem - hr * INT_GPR;
        int h = hr + 1;
        int w0 = 2 + 2 * gw;                     // covers pixels w0, w0+1
        const uint64_t* apn = ap + (size_t)n * HW + (h - 1) * WW + (w0 - 1);
        uint64_t a[3][4];
        #pragma unroll
        for (int rr = 0; rr < 3; ++rr)
            #pragma unroll
            for (int c = 0; c < 4; ++c)
                a[rr][c] = apn[rr * WW + c];
        float* op = out + (size_t)n * (OO * HW) + (size_t)(og * OPG) * HW + h * WW + w0;
        const uint64_t* wbase = wp + og * (OPG * 9); // scalar (wave-uniform)
        for (int oo = 0; oo < OPG; ++oo) {
            const uint64_t* wk = wbase + oo * 9;
            int s0 = 0, s1 = 0;
            #pragma unroll
            for (int rr = 0; rr < 3; ++rr)
                #pragma unroll
                for (int c = 0; c < 3; ++c) {
                    uint64_t w = wk[rr * 3 + c];
                    s0 += __popcll(a[rr][c]     ^ w);
                    s1 += __popcll(a[rr][c + 1] ^ w);
                }
            float2 v = make_float2((float)(576 - 2 * s0), (float)(576 - 2 * s1));
            *(float2*)(op + (size_t)oo * HW) = v;
        }
        return;
    }
    // ========= border: 1 pixel x 16 o-channels per thread, masked =========
    int t = blockIdx.x * 256 + threadIdx.x;      // [0, BOR_THREADS)
    int og = __builtin_amdgcn_readfirstlane(t / BOR_TOT); // wave-uniform
    int r = t - og * BOR_TOT;
    int n = r / BOR_PPI;
    int b = r - n * BOR_PPI;
    int h, w;
    if (b < 112)      { h = 0;   w = b; }
    else if (b < 224) { h = 111; w = b - 112; }
    else {
        int c = b - 224;
        h = 1 + (c >> 2);
        int q = c & 3;
        w = q + ((q >= 2) ? 108 : 0);            // q:0->0, 1->1, 2->110, 3->111
    }
    const uint64_t* apn = ap + (size_t)n * HW;
    uint64_t a[9], m[9];
    int nvalid = 0;
    #pragma unroll
    for (int kh = 0; kh < 3; ++kh) {
        int hh = h + kh - 1;
        bool hv = (unsigned)hh < (unsigned)HH;
        #pragma unroll
        for (int kw = 0; kw < 3; ++kw) {
            int ww2 = w + kw - 1;
            bool wv = (unsigned)ww2 < (unsigned)WW;
            bool v = hv && wv;
            int k = kh * 3 + kw;
            int ch = hv ? hh : h;                // clamped (safe) address
            int cw = wv ? ww2 : w;
            a[k] = apn[ch * WW + cw];
            m[k] = v ? ~0ull : 0ull;
            nvalid += v ? 1 : 0;
        }
    }
    int base = 64 * nvalid;
    float* op = out + (size_t)n * (OO * HW) + (size_t)(og * OPG) * HW + h * WW + w;
    const uint64_t* wbase = wp + og * (OPG * 9);
    for (int oo = 0; oo < OPG; ++oo) {
        const uint64_t* wk = wbase + oo * 9;
        int s = 0;
        #pragma unroll
        for (int k = 0; k < 9; ++k)
            s += __popcll((a[k] ^ wk[k]) & m[k]);
        op[(size_t)oo * HW] = (float)(base - 2 * s);
    }
}

extern "C" void kernel_launch(void* const* d_in, const int* in_sizes, int n_in,
                              void* d_out, int out_size, void* d_ws, size_t ws_size,
                              hipStream_t stream) {
    const float* act = (const float*)d_in[0];
    const float* wgt = (const float*)d_in[1];
    float* out = (float*)d_out;

    uint64_t* wp = (uint64_t*)d_ws;          // 576 words (rounded to 1024)
    uint64_t* ap = wp + 1024;                // 401408 words (~3.2 MB)

    pack_kernel<<<PACK_A_BLOCKS + 1, PACK_BLOCK, 0, stream>>>(act, wgt, ap, wp);
    conv_kernel<<<CONV_BLOCKS, 256, 0, stream>>>(ap, wp, out);
}